// Round 3
// baseline (4340.937 us; speedup 1.0000x reference)
//
#include <hip/hip_runtime.h>
#include <hip/hip_bf16.h>
#include <cstddef>

// Problem constants
#define BB 32
#define PP 196
#define DENC 256
#define EE 512
#define HH 512
#define AA 256
#define VV 30000
#define TT 20
#define BH (BB*HH)          // 16384
#define G4 (4*HH)           // 2048

typedef __attribute__((ext_vector_type(8))) short short8;
typedef __attribute__((ext_vector_type(4))) float f32x4;

__device__ __forceinline__ float fast_sigmoid(float x) {
    return 1.f / (1.f + __expf(-x));
}
__device__ __forceinline__ float fast_tanh(float x) {
    x = fminf(fmaxf(x, -15.f), 15.f);
    float e = __expf(2.f * x);
    return (e - 1.f) / (e + 1.f);
}
// round-to-nearest fp32 -> bf16 bits
__device__ __forceinline__ unsigned short f2bf(float x) {
    unsigned u = __float_as_uint(x);
    return (unsigned short)((u + 0x7fffu + ((u >> 16) & 1u)) >> 16);
}
__device__ __forceinline__ float bf2f(unsigned short h) {
    return __uint_as_float(((unsigned)h) << 16);
}

// ---------------------------------------------------------------------------
// att1[b,p,a] = enc[b,p,:] @ W_enc_att[:,a] + b_enc_att[a]
// ---------------------------------------------------------------------------
__global__ void att1_kernel(const float* __restrict__ enc,
                            const float* __restrict__ W,
                            const float* __restrict__ bias,
                            float* __restrict__ att1) {
    __shared__ float xs[8][DENC];
    const int tid = threadIdx.x;
    const int r0 = blockIdx.x * 8;
    #pragma unroll
    for (int bi = 0; bi < 8; ++bi)
        xs[bi][tid] = enc[(size_t)(r0 + bi) * DENC + tid];
    __syncthreads();
    float acc[8];
    const float bv = bias[tid];
    #pragma unroll
    for (int bi = 0; bi < 8; ++bi) acc[bi] = bv;
    #pragma unroll 8
    for (int k = 0; k < DENC; ++k) {
        const float w = W[k * AA + tid];
        #pragma unroll
        for (int bi = 0; bi < 8; ++bi) acc[bi] += xs[bi][k] * w;
    }
    #pragma unroll
    for (int bi = 0; bi < 8; ++bi)
        att1[(size_t)(r0 + bi) * AA + tid] = acc[bi];
}

// ---------------------------------------------------------------------------
// Epre[m, j] = emb[captions[b,t]] @ W_ih[0:512, j] + b_ih[j] + b_hh[j]
// ---------------------------------------------------------------------------
__global__ void epre_kernel(const int* __restrict__ captions,
                            const float* __restrict__ emb,
                            const float* __restrict__ Wih,
                            const float* __restrict__ bih,
                            const float* __restrict__ bhh,
                            float* __restrict__ Epre) {
    __shared__ float xs[8][EE];
    const int tid = threadIdx.x;
    const int jc = blockIdx.x;     // 0..7
    const int mg = blockIdx.y;     // 0..79
    const int j = jc * 256 + tid;

    #pragma unroll
    for (int i = 0; i < 8; ++i) {
        const int m = mg * 8 + i;
        const int t = m >> 5, b = m & 31;
        const int cap = captions[b * TT + t];
        const float* erow = emb + (size_t)cap * EE;
        xs[i][tid]       = erow[tid];
        xs[i][tid + 256] = erow[tid + 256];
    }
    __syncthreads();

    float acc[8];
    const float bv = bih[j] + bhh[j];
    #pragma unroll
    for (int i = 0; i < 8; ++i) acc[i] = bv;
    #pragma unroll 8
    for (int k = 0; k < EE; ++k) {
        const float w = Wih[(size_t)k * G4 + j];
        #pragma unroll
        for (int i = 0; i < 8; ++i) acc[i] += xs[i][k] * w;
    }
    #pragma unroll
    for (int i = 0; i < 8; ++i)
        Epre[(size_t)(mg * 8 + i) * G4 + j] = acc[i];
}

// ---------------------------------------------------------------------------
// Grid barrier: device-scope atomics, co-residency via cooperative launch.
// bar[0] = arrival counter, bar[1] = generation.
// ---------------------------------------------------------------------------
__device__ __forceinline__ void grid_barrier(unsigned* bar, unsigned nb) {
    __syncthreads();
    if (threadIdx.x == 0) {
        __threadfence();   // device-scope release (wb L2 for cross-XCD)
        unsigned g = __hip_atomic_load(&bar[1], __ATOMIC_RELAXED,
                                       __HIP_MEMORY_SCOPE_AGENT);
        unsigned a = __hip_atomic_fetch_add(&bar[0], 1u, __ATOMIC_ACQ_REL,
                                            __HIP_MEMORY_SCOPE_AGENT);
        if (a == nb - 1u) {
            __hip_atomic_store(&bar[0], 0u, __ATOMIC_RELAXED,
                               __HIP_MEMORY_SCOPE_AGENT);
            __hip_atomic_store(&bar[1], g + 1u, __ATOMIC_RELEASE,
                               __HIP_MEMORY_SCOPE_AGENT);
        } else {
            while (__hip_atomic_load(&bar[1], __ATOMIC_ACQUIRE,
                                     __HIP_MEMORY_SCOPE_AGENT) == g) {
                __builtin_amdgcn_s_sleep(4);
            }
        }
        __threadfence();   // device-scope acquire (inv caches)
    }
    __syncthreads();
}

// ---------------------------------------------------------------------------
// Persistent recurrence kernel: 256 blocks x 512 threads, cooperative.
// Per step: blocks 0..31 do attention (one per batch), barrier,
//           all 256 blocks do gates GEMM (jc = blk%32, bg = blk/32), barrier.
// ---------------------------------------------------------------------------
__global__ void loop_kernel(const float* __restrict__ att1,
                            const float* __restrict__ enc,
                            float* __restrict__ Hall,
                            float* __restrict__ cbuf,
                            float* __restrict__ context,
                            float* __restrict__ gates,
                            const float* __restrict__ Epre,
                            const float* __restrict__ Wda,
                            const float* __restrict__ bda,
                            const float* __restrict__ Wfull,
                            const float* __restrict__ bfull,
                            const float* __restrict__ Wih,
                            const float* __restrict__ Whh,
                            unsigned* bar) {
    __shared__ float h_s[HH];
    __shared__ float part[2][256];
    __shared__ float att2_s[AA];
    __shared__ float e_s[256];
    __shared__ float red_s[256];
    __shared__ float xs[4][768];
    __shared__ float part2[2][256];

    const int blk = blockIdx.x;    // 0..255
    const int tid = threadIdx.x;   // 0..511
    const unsigned NB = gridDim.x;

    for (int t = 0; t < TT; ++t) {
        // ================= attention phase (blocks 0..31) ==================
        if (blk < BB) {
            const int b = blk;
            // Phase 0: LSTM pointwise for t-1 (or init)
            if (t == 0) {
                h_s[tid] = 0.f;
                cbuf[b * HH + tid] = 0.f;
            } else {
                const float* g = gates + b * G4;
                const float gi = g[tid];
                const float gf = g[HH + tid];
                const float gg = g[2 * HH + tid];
                const float go = g[3 * HH + tid];
                const float cp = cbuf[b * HH + tid];
                const float cn = fast_sigmoid(gf) * cp + fast_sigmoid(gi) * fast_tanh(gg);
                const float hn = fast_sigmoid(go) * fast_tanh(cn);
                cbuf[b * HH + tid] = cn;
                Hall[(size_t)(t - 1) * BH + b * HH + tid] = hn;
                h_s[tid] = hn;
            }
            __syncthreads();

            // Phase 1: att2 = h @ Wda + bda  (2-way split-K)
            {
                const int half = tid >> 8, col = tid & 255;
                const float* W = Wda + (size_t)(half * 256) * AA + col;
                const float* hh = h_s + half * 256;
                float acc = 0.f;
                #pragma unroll 8
                for (int k = 0; k < 256; ++k) acc += hh[k] * W[(size_t)k * AA];
                part[half][col] = acc;
            }
            __syncthreads();
            if (tid < 256) att2_s[tid] = part[0][tid] + part[1][tid] + bda[tid];
            __syncthreads();

            // Phase 2: e[p]
            {
                const int wave = tid >> 6, lane = tid & 63;
                const float bf0 = bfull[0];
                for (int p = wave; p < PP; p += 8) {
                    const float* row = att1 + ((size_t)b * PP + p) * AA;
                    float s = 0.f;
                    #pragma unroll
                    for (int q = 0; q < 4; ++q) {
                        const int a = lane + q * 64;
                        s += fast_tanh(row[a] + att2_s[a]) * Wfull[a];
                    }
                    #pragma unroll
                    for (int off = 32; off > 0; off >>= 1) s += __shfl_down(s, off, 64);
                    if (lane == 0) e_s[p] = s + bf0;
                }
            }
            __syncthreads();

            // Phase 3: softmax
            const float val = (tid < PP) ? e_s[tid] : -3.4e38f;
            if (tid < 256) red_s[tid] = val;
            __syncthreads();
            #pragma unroll
            for (int s = 128; s > 0; s >>= 1) {
                if (tid < s) red_s[tid] = fmaxf(red_s[tid], red_s[tid + s]);
                __syncthreads();
            }
            const float mx = red_s[0];
            __syncthreads();
            const float ex = (tid < PP) ? __expf(val - mx) : 0.f;
            if (tid < 256) red_s[tid] = ex;
            __syncthreads();
            #pragma unroll
            for (int s = 128; s > 0; s >>= 1) {
                if (tid < s) red_s[tid] += red_s[tid + s];
                __syncthreads();
            }
            const float inv = 1.f / red_s[0];
            __syncthreads();
            if (tid < 256) e_s[tid] = ex * inv;
            __syncthreads();

            // Phase 4: context
            {
                const int half = tid >> 8, col = tid & 255;
                const float* erow = enc + (size_t)b * PP * DENC + col;
                float acc = 0.f;
                const int p0 = half * 98;
                #pragma unroll 7
                for (int p = p0; p < p0 + 98; ++p) acc += e_s[p] * erow[(size_t)p * DENC];
                part[half][col] = acc;
            }
            __syncthreads();
            if (tid < 256) context[b * DENC + tid] = part[0][tid] + part[1][tid];
        }
        grid_barrier(bar, NB);

        // ================= gates phase (all 256 blocks) ====================
        {
            const int jc = blk & 31;       // 0..31
            const int bg = blk >> 5;       // 0..7

            for (int idx = tid; idx < 4 * 768; idx += 512) {
                const int bi = idx / 768;
                const int k = idx - bi * 768;
                const int b = bg * 4 + bi;
                float v;
                if (k < 256) v = context[b * DENC + k];
                else v = (t > 0) ? Hall[(size_t)(t - 1) * BH + b * HH + (k - 256)] : 0.f;
                xs[bi][k] = v;
            }
            __syncthreads();

            const int khalf = tid >> 8;
            const int r = tid & 255;
            const int jl = r & 63, bl = r >> 6;
            const int j = jc * 64 + jl;
            const float* xrow = xs[bl];

            float acc = 0.f;
            if (khalf == 0) {
                const float* W1 = Wih + (size_t)512 * G4 + j;
                #pragma unroll 8
                for (int k = 0; k < 256; ++k) acc += xrow[k] * W1[(size_t)k * G4];
                const float* W2 = Whh + j;
                #pragma unroll 8
                for (int k = 0; k < 128; ++k) acc += xrow[256 + k] * W2[(size_t)k * G4];
            } else {
                const float* W2 = Whh + (size_t)128 * G4 + j;
                #pragma unroll 8
                for (int k = 0; k < 384; ++k) acc += xrow[384 + k] * W2[(size_t)k * G4];
            }
            part2[khalf][r] = acc;
            __syncthreads();

            if (tid < 256) {
                const int b = bg * 4 + bl;
                gates[(size_t)b * G4 + j] = part2[0][tid] + part2[1][tid]
                                          + Epre[(size_t)(t * BB + b) * G4 + j];
            }
            __syncthreads();
        }
        grid_barrier(bar, NB);
    }

    // Final LSTM pointwise update -> Hall[T-1]
    if (blk < BB) {
        const int b = blk, hi = tid;
        const float* g = gates + b * G4;
        const float gi = g[hi];
        const float gf = g[HH + hi];
        const float gg = g[2 * HH + hi];
        const float go = g[3 * HH + hi];
        const float cp = cbuf[b * HH + hi];
        const float cn = fast_sigmoid(gf) * cp + fast_sigmoid(gi) * fast_tanh(gg);
        const float hn = fast_sigmoid(go) * fast_tanh(cn);
        Hall[(size_t)(TT - 1) * BH + b * HH + hi] = hn;
    }
}

// ---------------------------------------------------------------------------
// Output projection with bf16x3 MFMA (split fp32 into hi/lo bf16;
// acc += ah*bh + ah*bl + al*bh). D[m][v], m = t*32+b, out[b][t][v].
// 128x128 tile, BK=32, 256 threads (4 waves, each 64x64 of 16x16x32 frags).
// A (Hall) and B (Wfc) converted + transposed into LDS in-flight.
// ---------------------------------------------------------------------------
#define LDK 40   // padded LDS row length in bf16 units (2-way bank alias only)

__global__ __launch_bounds__(256) void gemm_out_mfma(
        const float* __restrict__ Hall,
        const float* __restrict__ Wfc,
        const float* __restrict__ bfc,
        float* __restrict__ out) {
    __shared__ unsigned short As_h[128 * LDK];
    __shared__ unsigned short As_l[128 * LDK];
    __shared__ unsigned short Bs_h[128 * LDK];
    __shared__ unsigned short Bs_l[128 * LDK];

    const int tid = threadIdx.x;
    const int m0 = blockIdx.x * 128;     // 5 m-tiles (M=640)
    const int v0 = blockIdx.y * 128;     // 235 n-tiles

    const int wave = tid >> 6, lane = tid & 63;
    const int wm = wave & 1, wn = wave >> 1;
    const int row16 = lane & 15, quad = lane >> 4;

    const int sn = tid & 127;            // staging row (m for A, v for B)
    const int skq = tid >> 7;            // staging k-half (16 k's)

    f32x4 acc[4][4] = {};

    #pragma unroll 1
    for (int k0 = 0; k0 < HH; k0 += 32) {
        // ---- stage A: Hall[m0+sn][k0+skq*16 .. +16] -> hi/lo bf16
        {
            const float* asrc = Hall + (size_t)(m0 + sn) * HH + k0 + skq * 16;
            short8 h0, h1, l0, l1;
            #pragma unroll
            for (int i = 0; i < 16; i += 4) {
                const float4 v = *reinterpret_cast<const float4*>(asrc + i);
                const float vv[4] = {v.x, v.y, v.z, v.w};
                #pragma unroll
                for (int jj = 0; jj < 4; ++jj) {
                    const unsigned short hb = f2bf(vv[jj]);
                    const unsigned short lb = f2bf(vv[jj] - bf2f(hb));
                    const int e = i + jj;
                    if (e < 8) { h0[e] = (short)hb; l0[e] = (short)lb; }
                    else       { h1[e - 8] = (short)hb; l1[e - 8] = (short)lb; }
                }
            }
            unsigned short* dh = &As_h[sn * LDK + skq * 16];
            unsigned short* dl = &As_l[sn * LDK + skq * 16];
            *(short8*)(dh) = h0; *(short8*)(dh + 8) = h1;
            *(short8*)(dl) = l0; *(short8*)(dl + 8) = l1;
        }
        // ---- stage B: Wfc[k0+skq*16+i][v0+sn] (transpose) -> hi/lo bf16
        {
            const int vcol = v0 + sn;
            const bool ok = vcol < VV;
            const float* bsrc = Wfc + (size_t)(k0 + skq * 16) * VV + vcol;
            short8 h0, h1, l0, l1;
            #pragma unroll
            for (int i = 0; i < 16; ++i) {
                const float x = ok ? bsrc[(size_t)i * VV] : 0.f;
                const unsigned short hb = f2bf(x);
                const unsigned short lb = f2bf(x - bf2f(hb));
                if (i < 8) { h0[i] = (short)hb; l0[i] = (short)lb; }
                else       { h1[i - 8] = (short)hb; l1[i - 8] = (short)lb; }
            }
            unsigned short* dh = &Bs_h[sn * LDK + skq * 16];
            unsigned short* dl = &Bs_l[sn * LDK + skq * 16];
            *(short8*)(dh) = h0; *(short8*)(dh + 8) = h1;
            *(short8*)(dl) = l0; *(short8*)(dl + 8) = l1;
        }
        __syncthreads();

        // ---- fragments + MFMA
        short8 ah[4], al[4], bh[4], bl[4];
        #pragma unroll
        for (int mi = 0; mi < 4; ++mi) {
            const int off = (wm * 64 + mi * 16 + row16) * LDK + quad * 8;
            ah[mi] = *(const short8*)&As_h[off];
            al[mi] = *(const short8*)&As_l[off];
        }
        #pragma unroll
        for (int ni = 0; ni < 4; ++ni) {
            const int off = (wn * 64 + ni * 16 + row16) * LDK + quad * 8;
            bh[ni] = *(const short8*)&Bs_h[off];
            bl[ni] = *(const short8*)&Bs_l[off];
        }
        #pragma unroll
        for (int mi = 0; mi < 4; ++mi) {
            #pragma unroll
            for (int ni = 0; ni < 4; ++ni) {
                acc[mi][ni] = __builtin_amdgcn_mfma_f32_16x16x32_bf16(
                    ah[mi], bh[ni], acc[mi][ni], 0, 0, 0);
                acc[mi][ni] = __builtin_amdgcn_mfma_f32_16x16x32_bf16(
                    ah[mi], bl[ni], acc[mi][ni], 0, 0, 0);
                acc[mi][ni] = __builtin_amdgcn_mfma_f32_16x16x32_bf16(
                    al[mi], bh[ni], acc[mi][ni], 0, 0, 0);
            }
        }
        __syncthreads();
    }

    // ---- epilogue: C/D layout col=lane&15 (v), row=quad*4+reg (m)
    #pragma unroll
    for (int ni = 0; ni < 4; ++ni) {
        const int v = v0 + wn * 64 + ni * 16 + row16;
        if (v >= VV) continue;
        const float bias = bfc[v];
        #pragma unroll
        for (int mi = 0; mi < 4; ++mi) {
            const int mbase = m0 + wm * 64 + mi * 16 + quad * 4;
            #pragma unroll
            for (int r = 0; r < 4; ++r) {
                const int m = mbase + r;
                const int t_idx = m >> 5;
                const int b_idx = m & 31;
                out[((size_t)b_idx * TT + t_idx) * VV + v] = acc[mi][ni][r] + bias;
            }
        }
    }
}

// ---------------------------------------------------------------------------
extern "C" void kernel_launch(void* const* d_in, const int* in_sizes, int n_in,
                              void* d_out, int out_size, void* d_ws, size_t ws_size,
                              hipStream_t stream) {
    const float* enc      = (const float*)d_in[0];
    const int*   captions = (const int*)  d_in[1];
    const float* Wea      = (const float*)d_in[2];
    const float* bea      = (const float*)d_in[3];
    const float* Wda      = (const float*)d_in[4];
    const float* bda      = (const float*)d_in[5];
    const float* Wfull    = (const float*)d_in[6];
    const float* bfull    = (const float*)d_in[7];
    const float* emb      = (const float*)d_in[8];
    const float* Wih      = (const float*)d_in[9];
    const float* bih      = (const float*)d_in[10];
    const float* Whh      = (const float*)d_in[11];
    const float* bhh      = (const float*)d_in[12];
    const float* Wfc      = (const float*)d_in[13];
    const float* bfc      = (const float*)d_in[14];
    float* out = (float*)d_out;

    float* ws      = (float*)d_ws;
    float* att1    = ws;                        // 32*196*256     = 1,605,632
    float* Hall    = att1 + 1605632;            // 20*32*512      =   327,680
    float* cbuf    = Hall + 327680;             // 32*512         =    16,384
    float* context = cbuf + 16384;              // 32*256         =     8,192
    float* gates   = context + 8192;            // 32*2048        =    65,536
    float* Epre    = gates + 65536;             // 640*2048       = 1,310,720

    // barrier storage: last 8 bytes of d_out (rewritten by gemm afterwards)
    unsigned* bar = (unsigned*)(out + (size_t)out_size - 2);

    att1_kernel<<<dim3(784), dim3(256), 0, stream>>>(enc, Wea, bea, att1);
    epre_kernel<<<dim3(8, 80), dim3(256), 0, stream>>>(captions, emb, Wih, bih, bhh, Epre);
    hipMemsetAsync((void*)bar, 0, 2 * sizeof(unsigned), stream);

    {
        void* cargs[] = {
            (void*)&att1, (void*)&enc, (void*)&Hall, (void*)&cbuf,
            (void*)&context, (void*)&gates, (void*)&Epre,
            (void*)&Wda, (void*)&bda, (void*)&Wfull, (void*)&bfull,
            (void*)&Wih, (void*)&Whh, (void*)&bar
        };
        hipLaunchCooperativeKernel((const void*)loop_kernel, dim3(256), dim3(512),
                                   cargs, 0, stream);
    }

    gemm_out_mfma<<<dim3(5, 235), dim3(256), 0, stream>>>(Hall, Wfc, bfc, out);
}

// Round 4
// 1294.467 us; speedup vs baseline: 3.3535x; 3.3535x over previous
//
#include <hip/hip_runtime.h>
#include <hip/hip_bf16.h>
#include <cstddef>

// Problem constants
#define BB 32
#define PP 196
#define DENC 256
#define EE 512
#define HH 512
#define AA 256
#define VV 30000
#define TT 20
#define BH (BB*HH)          // 16384
#define G4 (4*HH)           // 2048

typedef __attribute__((ext_vector_type(8))) short short8;
typedef __attribute__((ext_vector_type(4))) float f32x4;

__device__ __forceinline__ float fast_sigmoid(float x) {
    return 1.f / (1.f + __expf(-x));
}
__device__ __forceinline__ float fast_tanh(float x) {
    x = fminf(fmaxf(x, -15.f), 15.f);
    float e = __expf(2.f * x);
    return (e - 1.f) / (e + 1.f);
}
// truncation split: hi = bf16_trunc(x), lo = bf16_trunc(x - hi)
// error of ah*bh + ah*bl + al*bh vs fp32 ~ 2^-16 relative — well under threshold
__device__ __forceinline__ void split_bf16(float x, unsigned short& hi, unsigned short& lo) {
    const unsigned u = __float_as_uint(x);
    hi = (unsigned short)(u >> 16);
    const float r = x - __uint_as_float(u & 0xffff0000u);
    lo = (unsigned short)(__float_as_uint(r) >> 16);
}

// ---------------------------------------------------------------------------
// att1[b,p,a] = enc[b,p,:] @ W_enc_att[:,a] + b_enc_att[a]
// ---------------------------------------------------------------------------
__global__ void att1_kernel(const float* __restrict__ enc,
                            const float* __restrict__ W,
                            const float* __restrict__ bias,
                            float* __restrict__ att1) {
    __shared__ float xs[8][DENC];
    const int tid = threadIdx.x;
    const int r0 = blockIdx.x * 8;
    #pragma unroll
    for (int bi = 0; bi < 8; ++bi)
        xs[bi][tid] = enc[(size_t)(r0 + bi) * DENC + tid];
    __syncthreads();
    float acc[8];
    const float bv = bias[tid];
    #pragma unroll
    for (int bi = 0; bi < 8; ++bi) acc[bi] = bv;
    #pragma unroll 8
    for (int k = 0; k < DENC; ++k) {
        const float w = W[k * AA + tid];
        #pragma unroll
        for (int bi = 0; bi < 8; ++bi) acc[bi] += xs[bi][k] * w;
    }
    #pragma unroll
    for (int bi = 0; bi < 8; ++bi)
        att1[(size_t)(r0 + bi) * AA + tid] = acc[bi];
}

// ---------------------------------------------------------------------------
// Epre[m, j] = emb[captions[b,t]] @ W_ih[0:512, j] + b_ih[j] + b_hh[j]
// ---------------------------------------------------------------------------
__global__ void epre_kernel(const int* __restrict__ captions,
                            const float* __restrict__ emb,
                            const float* __restrict__ Wih,
                            const float* __restrict__ bih,
                            const float* __restrict__ bhh,
                            float* __restrict__ Epre) {
    __shared__ float xs[8][EE];
    const int tid = threadIdx.x;
    const int jc = blockIdx.x;     // 0..7
    const int mg = blockIdx.y;     // 0..79
    const int j = jc * 256 + tid;

    #pragma unroll
    for (int i = 0; i < 8; ++i) {
        const int m = mg * 8 + i;
        const int t = m >> 5, b = m & 31;
        const int cap = captions[b * TT + t];
        const float* erow = emb + (size_t)cap * EE;
        xs[i][tid]       = erow[tid];
        xs[i][tid + 256] = erow[tid + 256];
    }
    __syncthreads();

    float acc[8];
    const float bv = bih[j] + bhh[j];
    #pragma unroll
    for (int i = 0; i < 8; ++i) acc[i] = bv;
    #pragma unroll 8
    for (int k = 0; k < EE; ++k) {
        const float w = Wih[(size_t)k * G4 + j];
        #pragma unroll
        for (int i = 0; i < 8; ++i) acc[i] += xs[i][k] * w;
    }
    #pragma unroll
    for (int i = 0; i < 8; ++i)
        Epre[(size_t)(mg * 8 + i) * G4 + j] = acc[i];
}

// ---------------------------------------------------------------------------
// Per-timestep attention kernel. One block per batch (32 blocks, 512 threads).
// ---------------------------------------------------------------------------
__global__ void attn_step_kernel(int t,
                                 const float* __restrict__ att1,
                                 const float* __restrict__ enc,
                                 float* __restrict__ Hall,
                                 float* __restrict__ cbuf,
                                 const float* __restrict__ gates,
                                 float* __restrict__ context,
                                 const float* __restrict__ Wda,
                                 const float* __restrict__ bda,
                                 const float* __restrict__ Wfull,
                                 const float* __restrict__ bfull) {
    __shared__ float h_s[HH];
    __shared__ float part[2][256];
    __shared__ float att2_s[AA];
    __shared__ float e_s[256];
    __shared__ float red_s[256];
    const int b = blockIdx.x;
    const int tid = threadIdx.x;   // 0..511

    // Phase 0: LSTM pointwise for t-1 (or init)
    if (t == 0) {
        h_s[tid] = 0.f;
        cbuf[b * HH + tid] = 0.f;
    } else {
        const float* g = gates + b * G4;
        const float gi = g[tid];
        const float gf = g[HH + tid];
        const float gg = g[2 * HH + tid];
        const float go = g[3 * HH + tid];
        const float cp = cbuf[b * HH + tid];
        const float cn = fast_sigmoid(gf) * cp + fast_sigmoid(gi) * fast_tanh(gg);
        const float hn = fast_sigmoid(go) * fast_tanh(cn);
        cbuf[b * HH + tid] = cn;
        Hall[(size_t)(t - 1) * BH + b * HH + tid] = hn;
        h_s[tid] = hn;
    }
    __syncthreads();

    // Phase 1: att2 = h @ Wda + bda (2-way split-K)
    {
        const int half = tid >> 8, col = tid & 255;
        const float* W = Wda + (size_t)(half * 256) * AA + col;
        const float* hh = h_s + half * 256;
        float acc = 0.f;
        #pragma unroll 16
        for (int k = 0; k < 256; ++k) acc += hh[k] * W[(size_t)k * AA];
        part[half][col] = acc;
    }
    __syncthreads();
    if (tid < 256) att2_s[tid] = part[0][tid] + part[1][tid] + bda[tid];
    __syncthreads();

    // Phase 2: e[p], one wave per p (8 waves)
    {
        const int wave = tid >> 6, lane = tid & 63;
        const float bf0 = bfull[0];
        for (int p = wave; p < PP; p += 8) {
            const float* row = att1 + ((size_t)b * PP + p) * AA;
            float s = 0.f;
            #pragma unroll
            for (int q = 0; q < 4; ++q) {
                const int a = lane + q * 64;
                s += fast_tanh(row[a] + att2_s[a]) * Wfull[a];
            }
            #pragma unroll
            for (int off = 32; off > 0; off >>= 1) s += __shfl_down(s, off, 64);
            if (lane == 0) e_s[p] = s + bf0;
        }
    }
    __syncthreads();

    // Phase 3: softmax over p
    const float val = (tid < PP) ? e_s[tid] : -3.4e38f;
    if (tid < 256) red_s[tid] = val;
    __syncthreads();
    #pragma unroll
    for (int s = 128; s > 0; s >>= 1) {
        if (tid < s) red_s[tid] = fmaxf(red_s[tid], red_s[tid + s]);
        __syncthreads();
    }
    const float mx = red_s[0];
    __syncthreads();
    const float ex = (tid < PP) ? __expf(val - mx) : 0.f;
    if (tid < 256) red_s[tid] = ex;
    __syncthreads();
    #pragma unroll
    for (int s = 128; s > 0; s >>= 1) {
        if (tid < s) red_s[tid] += red_s[tid + s];
        __syncthreads();
    }
    const float inv = 1.f / red_s[0];
    __syncthreads();
    if (tid < 256) e_s[tid] = ex * inv;
    __syncthreads();

    // Phase 4: context = alpha @ enc (2-way split over p)
    {
        const int half = tid >> 8, col = tid & 255;
        const float* erow = enc + (size_t)b * PP * DENC + col;
        float acc = 0.f;
        const int p0 = half * 98;
        #pragma unroll 7
        for (int p = p0; p < p0 + 98; ++p) acc += e_s[p] * erow[(size_t)p * DENC];
        part[half][col] = acc;
    }
    __syncthreads();
    if (tid < 256) context[b * DENC + tid] = part[0][tid] + part[1][tid];
}

// ---------------------------------------------------------------------------
// gates[b, j] = Epre[t*32+b, j] + context @ W_ih[512:768, j] + h @ W_hh[:, j]
// Grid (32 jc, 8 bg), 512 threads: 64 j x 4 b x 2 k-halves.
// ---------------------------------------------------------------------------
__global__ void gates_kernel(int t,
                             const float* __restrict__ context,
                             const float* __restrict__ Hall,
                             const float* __restrict__ Epre,
                             const float* __restrict__ Wih,
                             const float* __restrict__ Whh,
                             float* __restrict__ gates) {
    __shared__ float xs[4][768];
    __shared__ float part[2][256];
    const int tid = threadIdx.x;     // 0..511
    const int jc = blockIdx.x;       // 0..31
    const int bg = blockIdx.y;       // 0..7

    for (int idx = tid; idx < 4 * 768; idx += 512) {
        const int bi = idx / 768;
        const int k = idx - bi * 768;
        const int b = bg * 4 + bi;
        float v;
        if (k < 256) v = context[b * DENC + k];
        else v = (t > 0) ? Hall[(size_t)(t - 1) * BH + b * HH + (k - 256)] : 0.f;
        xs[bi][k] = v;
    }
    __syncthreads();

    const int khalf = tid >> 8;
    const int r = tid & 255;
    const int jl = r & 63, bl = r >> 6;
    const int j = jc * 64 + jl;
    const float* xrow = xs[bl];

    float acc = 0.f;
    if (khalf == 0) {
        const float* W1 = Wih + (size_t)512 * G4 + j;
        #pragma unroll 16
        for (int k = 0; k < 256; ++k) acc += xrow[k] * W1[(size_t)k * G4];
        const float* W2 = Whh + j;
        #pragma unroll 16
        for (int k = 0; k < 128; ++k) acc += xrow[256 + k] * W2[(size_t)k * G4];
    } else {
        const float* W2 = Whh + (size_t)128 * G4 + j;
        #pragma unroll 16
        for (int k = 0; k < 384; ++k) acc += xrow[384 + k] * W2[(size_t)k * G4];
    }
    part[khalf][r] = acc;
    __syncthreads();

    if (tid < 256) {
        const int b = bg * 4 + bl;
        gates[(size_t)b * G4 + j] = part[0][tid] + part[1][tid]
                                  + Epre[(size_t)(t * BB + b) * G4 + j];
    }
}

// ---------------------------------------------------------------------------
// LSTM pointwise update for the final step (t = T-1) -> Hall[T-1]
// ---------------------------------------------------------------------------
__global__ void final_update_kernel(const float* __restrict__ gates,
                                    const float* __restrict__ cbuf,
                                    float* __restrict__ Hall) {
    const int idx = blockIdx.x * 256 + threadIdx.x;   // < 16384
    const int b = idx >> 9, hi = idx & 511;
    const float* g = gates + b * G4;
    const float gi = g[hi];
    const float gf = g[HH + hi];
    const float gg = g[2 * HH + hi];
    const float go = g[3 * HH + hi];
    const float cp = cbuf[idx];
    const float cn = fast_sigmoid(gf) * cp + fast_sigmoid(gi) * fast_tanh(gg);
    const float hn = fast_sigmoid(go) * fast_tanh(cn);
    Hall[(size_t)(TT - 1) * BH + idx] = hn;
}

// ---------------------------------------------------------------------------
// Output projection with bf16x3 MFMA (truncation hi/lo split;
// acc += ah*bh + ah*bl + al*bh). 128x128 tile, BK=32, 256 threads.
// ---------------------------------------------------------------------------
#define LDK 40   // padded LDS row length in bf16 units

__global__ __launch_bounds__(256) void gemm_out_mfma(
        const float* __restrict__ Hall,
        const float* __restrict__ Wfc,
        const float* __restrict__ bfc,
        float* __restrict__ out) {
    __shared__ unsigned short As_h[128 * LDK];
    __shared__ unsigned short As_l[128 * LDK];
    __shared__ unsigned short Bs_h[128 * LDK];
    __shared__ unsigned short Bs_l[128 * LDK];

    const int tid = threadIdx.x;
    const int m0 = blockIdx.x * 128;     // 5 m-tiles (M=640)
    const int v0 = blockIdx.y * 128;     // 235 n-tiles

    const int wave = tid >> 6, lane = tid & 63;
    const int wm = wave & 1, wn = wave >> 1;
    const int row16 = lane & 15, quad = lane >> 4;

    const int sn = tid & 127;            // staging row (m for A, v for B)
    const int skq = tid >> 7;            // staging k-half (16 k's)

    f32x4 acc[4][4] = {};

    #pragma unroll 1
    for (int k0 = 0; k0 < HH; k0 += 32) {
        // ---- stage A
        {
            const float* asrc = Hall + (size_t)(m0 + sn) * HH + k0 + skq * 16;
            short8 h0, h1, l0, l1;
            #pragma unroll
            for (int i = 0; i < 16; i += 4) {
                const float4 v = *reinterpret_cast<const float4*>(asrc + i);
                const float vv[4] = {v.x, v.y, v.z, v.w};
                #pragma unroll
                for (int jj = 0; jj < 4; ++jj) {
                    unsigned short hb, lb;
                    split_bf16(vv[jj], hb, lb);
                    const int e = i + jj;
                    if (e < 8) { h0[e] = (short)hb; l0[e] = (short)lb; }
                    else       { h1[e - 8] = (short)hb; l1[e - 8] = (short)lb; }
                }
            }
            unsigned short* dh = &As_h[sn * LDK + skq * 16];
            unsigned short* dl = &As_l[sn * LDK + skq * 16];
            *(short8*)(dh) = h0; *(short8*)(dh + 8) = h1;
            *(short8*)(dl) = l0; *(short8*)(dl + 8) = l1;
        }
        // ---- stage B (transpose Wfc)
        {
            const int vcol = v0 + sn;
            const bool ok = vcol < VV;
            const float* bsrc = Wfc + (size_t)(k0 + skq * 16) * VV + vcol;
            short8 h0, h1, l0, l1;
            #pragma unroll
            for (int i = 0; i < 16; ++i) {
                const float x = ok ? bsrc[(size_t)i * VV] : 0.f;
                unsigned short hb, lb;
                split_bf16(x, hb, lb);
                if (i < 8) { h0[i] = (short)hb; l0[i] = (short)lb; }
                else       { h1[i - 8] = (short)hb; l1[i - 8] = (short)lb; }
            }
            unsigned short* dh = &Bs_h[sn * LDK + skq * 16];
            unsigned short* dl = &Bs_l[sn * LDK + skq * 16];
            *(short8*)(dh) = h0; *(short8*)(dh + 8) = h1;
            *(short8*)(dl) = l0; *(short8*)(dl + 8) = l1;
        }
        __syncthreads();

        short8 ah[4], al[4], bh[4], bl[4];
        #pragma unroll
        for (int mi = 0; mi < 4; ++mi) {
            const int off = (wm * 64 + mi * 16 + row16) * LDK + quad * 8;
            ah[mi] = *(const short8*)&As_h[off];
            al[mi] = *(const short8*)&As_l[off];
        }
        #pragma unroll
        for (int ni = 0; ni < 4; ++ni) {
            const int off = (wn * 64 + ni * 16 + row16) * LDK + quad * 8;
            bh[ni] = *(const short8*)&Bs_h[off];
            bl[ni] = *(const short8*)&Bs_l[off];
        }
        #pragma unroll
        for (int mi = 0; mi < 4; ++mi) {
            #pragma unroll
            for (int ni = 0; ni < 4; ++ni) {
                acc[mi][ni] = __builtin_amdgcn_mfma_f32_16x16x32_bf16(
                    ah[mi], bh[ni], acc[mi][ni], 0, 0, 0);
                acc[mi][ni] = __builtin_amdgcn_mfma_f32_16x16x32_bf16(
                    ah[mi], bl[ni], acc[mi][ni], 0, 0, 0);
                acc[mi][ni] = __builtin_amdgcn_mfma_f32_16x16x32_bf16(
                    al[mi], bh[ni], acc[mi][ni], 0, 0, 0);
            }
        }
        __syncthreads();
    }

    // epilogue: C/D layout col=lane&15 (v), row=quad*4+reg (m)
    #pragma unroll
    for (int ni = 0; ni < 4; ++ni) {
        const int v = v0 + wn * 64 + ni * 16 + row16;
        if (v >= VV) continue;
        const float bias = bfc[v];
        #pragma unroll
        for (int mi = 0; mi < 4; ++mi) {
            const int mbase = m0 + wm * 64 + mi * 16 + quad * 4;
            #pragma unroll
            for (int r = 0; r < 4; ++r) {
                const int m = mbase + r;
                const int t_idx = m >> 5;
                const int b_idx = m & 31;
                out[((size_t)b_idx * TT + t_idx) * VV + v] = acc[mi][ni][r] + bias;
            }
        }
    }
}

// ---------------------------------------------------------------------------
extern "C" void kernel_launch(void* const* d_in, const int* in_sizes, int n_in,
                              void* d_out, int out_size, void* d_ws, size_t ws_size,
                              hipStream_t stream) {
    const float* enc      = (const float*)d_in[0];
    const int*   captions = (const int*)  d_in[1];
    const float* Wea      = (const float*)d_in[2];
    const float* bea      = (const float*)d_in[3];
    const float* Wda      = (const float*)d_in[4];
    const float* bda      = (const float*)d_in[5];
    const float* Wfull    = (const float*)d_in[6];
    const float* bfull    = (const float*)d_in[7];
    const float* emb      = (const float*)d_in[8];
    const float* Wih      = (const float*)d_in[9];
    const float* bih      = (const float*)d_in[10];
    const float* Whh      = (const float*)d_in[11];
    const float* bhh      = (const float*)d_in[12];
    const float* Wfc      = (const float*)d_in[13];
    const float* bfc      = (const float*)d_in[14];
    float* out = (float*)d_out;

    float* ws      = (float*)d_ws;
    float* att1    = ws;                        // 32*196*256     = 1,605,632
    float* Hall    = att1 + 1605632;            // 20*32*512      =   327,680
    float* cbuf    = Hall + 327680;             // 32*512         =    16,384
    float* context = cbuf + 16384;              // 32*256         =     8,192
    float* gates   = context + 8192;            // 32*2048        =    65,536
    float* Epre    = gates + 65536;             // 640*2048       = 1,310,720

    att1_kernel<<<dim3(784), dim3(256), 0, stream>>>(enc, Wea, bea, att1);
    epre_kernel<<<dim3(8, 80), dim3(256), 0, stream>>>(captions, emb, Wih, bih, bhh, Epre);

    for (int t = 0; t < TT; ++t) {
        attn_step_kernel<<<dim3(BB), dim3(512), 0, stream>>>(
            t, att1, enc, Hall, cbuf, gates, context, Wda, bda, Wfull, bfull);
        gates_kernel<<<dim3(32, 8), dim3(512), 0, stream>>>(
            t, context, Hall, Epre, Wih, Whh, gates);
    }
    final_update_kernel<<<dim3(64), dim3(256), 0, stream>>>(gates, cbuf, Hall);

    gemm_out_mfma<<<dim3(5, 235), dim3(256), 0, stream>>>(Hall, Wfc, bfc, out);
}

// Round 5
// 1025.925 us; speedup vs baseline: 4.2312x; 1.2618x over previous
//
#include <hip/hip_runtime.h>
#include <hip/hip_bf16.h>
#include <cstddef>

// Problem constants
#define BB 32
#define PP 196
#define DENC 256
#define EE 512
#define HH 512
#define AA 256
#define VV 30000
#define TT 20
#define BH (BB*HH)          // 16384
#define G4 (4*HH)           // 2048
#define VPAD 30080          // VV padded to multiple of 64 (covers v0+127 overrun)

typedef __attribute__((ext_vector_type(8))) short short8;
typedef __attribute__((ext_vector_type(4))) float f32x4;

__device__ __forceinline__ float fast_sigmoid(float x) {
    return 1.f / (1.f + __expf(-x));
}
__device__ __forceinline__ float fast_tanh(float x) {
    x = fminf(fmaxf(x, -15.f), 15.f);
    float e = __expf(2.f * x);
    return (e - 1.f) / (e + 1.f);
}
// truncation split: hi = bf16_trunc(x), lo = bf16_trunc(x - hi)
__device__ __forceinline__ void split_bf16(float x, unsigned short& hi, unsigned short& lo) {
    const unsigned u = __float_as_uint(x);
    hi = (unsigned short)(u >> 16);
    const float r = x - __uint_as_float(u & 0xffff0000u);
    lo = (unsigned short)(__float_as_uint(r) >> 16);
}

// ---------------------------------------------------------------------------
// att1[b,p,a] = enc[b,p,:] @ W_enc_att[:,a] + b_enc_att[a]
// ---------------------------------------------------------------------------
__global__ void att1_kernel(const float* __restrict__ enc,
                            const float* __restrict__ W,
                            const float* __restrict__ bias,
                            float* __restrict__ att1) {
    __shared__ float xs[8][DENC];
    const int tid = threadIdx.x;
    const int r0 = blockIdx.x * 8;
    #pragma unroll
    for (int bi = 0; bi < 8; ++bi)
        xs[bi][tid] = enc[(size_t)(r0 + bi) * DENC + tid];
    __syncthreads();
    float acc[8];
    const float bv = bias[tid];
    #pragma unroll
    for (int bi = 0; bi < 8; ++bi) acc[bi] = bv;
    #pragma unroll 8
    for (int k = 0; k < DENC; ++k) {
        const float w = W[k * AA + tid];
        #pragma unroll
        for (int bi = 0; bi < 8; ++bi) acc[bi] += xs[bi][k] * w;
    }
    #pragma unroll
    for (int bi = 0; bi < 8; ++bi)
        att1[(size_t)(r0 + bi) * AA + tid] = acc[bi];
}

// ---------------------------------------------------------------------------
// Epre[m, j] = emb[captions[b,t]] @ W_ih[0:512, j] + b_ih[j] + b_hh[j]
// ---------------------------------------------------------------------------
__global__ void epre_kernel(const int* __restrict__ captions,
                            const float* __restrict__ emb,
                            const float* __restrict__ Wih,
                            const float* __restrict__ bih,
                            const float* __restrict__ bhh,
                            float* __restrict__ Epre) {
    __shared__ float xs[8][EE];
    const int tid = threadIdx.x;
    const int jc = blockIdx.x;     // 0..7
    const int mg = blockIdx.y;     // 0..79
    const int j = jc * 256 + tid;

    #pragma unroll
    for (int i = 0; i < 8; ++i) {
        const int m = mg * 8 + i;
        const int t = m >> 5, b = m & 31;
        const int cap = captions[b * TT + t];
        const float* erow = emb + (size_t)cap * EE;
        xs[i][tid]       = erow[tid];
        xs[i][tid + 256] = erow[tid + 256];
    }
    __syncthreads();

    float acc[8];
    const float bv = bih[j] + bhh[j];
    #pragma unroll
    for (int i = 0; i < 8; ++i) acc[i] = bv;
    #pragma unroll 8
    for (int k = 0; k < EE; ++k) {
        const float w = Wih[(size_t)k * G4 + j];
        #pragma unroll
        for (int i = 0; i < 8; ++i) acc[i] += xs[i][k] * w;
    }
    #pragma unroll
    for (int i = 0; i < 8; ++i)
        Epre[(size_t)(mg * 8 + i) * G4 + j] = acc[i];
}

// ---------------------------------------------------------------------------
// Per-timestep attention kernel: 32 blocks x 1024 threads (16 waves).
// Deeper splits to shorten dependent-load chains (latency-bound kernel).
// ---------------------------------------------------------------------------
__global__ __launch_bounds__(1024) void attn_step_kernel(
        int t,
        const float* __restrict__ att1,
        const float* __restrict__ enc,
        float* __restrict__ Hall,
        float* __restrict__ cbuf,
        const float* __restrict__ gates,
        float* __restrict__ context,
        const float* __restrict__ Wda,
        const float* __restrict__ bda,
        const float* __restrict__ Wfull,
        const float* __restrict__ bfull) {
    __shared__ float h_s[HH];
    __shared__ float part[4][256];
    __shared__ float att2_s[AA];
    __shared__ float e_s[256];
    __shared__ float red_s[256];
    const int b = blockIdx.x;
    const int tid = threadIdx.x;   // 0..1023

    // Phase 0: LSTM pointwise for t-1 (or init) — threads 0..511
    if (tid < 512) {
        if (t == 0) {
            h_s[tid] = 0.f;
            cbuf[b * HH + tid] = 0.f;
        } else {
            const float* g = gates + b * G4;
            const float gi = g[tid];
            const float gf = g[HH + tid];
            const float gg = g[2 * HH + tid];
            const float go = g[3 * HH + tid];
            const float cp = cbuf[b * HH + tid];
            const float cn = fast_sigmoid(gf) * cp + fast_sigmoid(gi) * fast_tanh(gg);
            const float hn = fast_sigmoid(go) * fast_tanh(cn);
            cbuf[b * HH + tid] = cn;
            Hall[(size_t)(t - 1) * BH + b * HH + tid] = hn;
            h_s[tid] = hn;
        }
    }
    __syncthreads();

    // Phase 1: att2 = h @ Wda + bda  (4-way split-K, 128 each)
    {
        const int q = tid >> 8, col = tid & 255;
        const float* W = Wda + (size_t)(q * 128) * AA + col;
        const float* hh = h_s + q * 128;
        float acc = 0.f;
        #pragma unroll 16
        for (int k = 0; k < 128; ++k) acc += hh[k] * W[(size_t)k * AA];
        part[q][col] = acc;
    }
    __syncthreads();
    if (tid < 256)
        att2_s[tid] = part[0][tid] + part[1][tid] + part[2][tid] + part[3][tid] + bda[tid];
    __syncthreads();

    // Phase 2: e[p], one wave per p (16 waves)
    {
        const int wave = tid >> 6, lane = tid & 63;
        const float bf0 = bfull[0];
        for (int p = wave; p < PP; p += 16) {
            const float* row = att1 + ((size_t)b * PP + p) * AA;
            float s = 0.f;
            #pragma unroll
            for (int q = 0; q < 4; ++q) {
                const int a = lane + q * 64;
                s += fast_tanh(row[a] + att2_s[a]) * Wfull[a];
            }
            #pragma unroll
            for (int off = 32; off > 0; off >>= 1) s += __shfl_down(s, off, 64);
            if (lane == 0) e_s[p] = s + bf0;
        }
    }
    __syncthreads();

    // Phase 3: softmax over p (tree in first 256 threads; uniform sync loop)
    const float val = (tid < PP) ? e_s[tid] : -3.4e38f;
    if (tid < 256) red_s[tid] = val;
    __syncthreads();
    #pragma unroll
    for (int s = 128; s > 0; s >>= 1) {
        if (tid < s) red_s[tid] = fmaxf(red_s[tid], red_s[tid + s]);
        __syncthreads();
    }
    const float mx = red_s[0];
    __syncthreads();
    const float ex = (tid < PP) ? __expf(val - mx) : 0.f;
    if (tid < 256) red_s[tid] = ex;
    __syncthreads();
    #pragma unroll
    for (int s = 128; s > 0; s >>= 1) {
        if (tid < s) red_s[tid] += red_s[tid + s];
        __syncthreads();
    }
    const float inv = 1.f / red_s[0];
    __syncthreads();
    if (tid < 256) e_s[tid] = ex * inv;   // alpha (0 for p >= 196)
    __syncthreads();

    // Phase 4: context = alpha @ enc  (4-way split over p, 49 each)
    {
        const int q = tid >> 8, col = tid & 255;
        const float* erow = enc + (size_t)b * PP * DENC + col;
        float acc = 0.f;
        const int p0 = q * 49;
        #pragma unroll 7
        for (int p = p0; p < p0 + 49; ++p) acc += e_s[p] * erow[(size_t)p * DENC];
        part[q][col] = acc;
    }
    __syncthreads();
    if (tid < 256)
        context[b * DENC + tid] = part[0][tid] + part[1][tid] + part[2][tid] + part[3][tid];
}

// ---------------------------------------------------------------------------
// gates[b, j] = Epre[t*32+b, j] + context @ W_ih[512:768, j] + h @ W_hh[:, j]
// Grid (32 jc, 8 bg), 1024 threads: 64 j x 4 b x 4 k-quarters (192 each).
// ---------------------------------------------------------------------------
__global__ __launch_bounds__(1024) void gates_kernel(
        int t,
        const float* __restrict__ context,
        const float* __restrict__ Hall,
        const float* __restrict__ Epre,
        const float* __restrict__ Wih,
        const float* __restrict__ Whh,
        float* __restrict__ gates) {
    __shared__ float xs[4][768];
    __shared__ float part[4][256];
    const int tid = threadIdx.x;     // 0..1023
    const int jc = blockIdx.x;       // 0..31
    const int bg = blockIdx.y;       // 0..7

    // Stage x = [context(256), h(512)] for 4 batches
    for (int idx = tid; idx < 4 * 768; idx += 1024) {
        const int bi = idx / 768;
        const int k = idx - bi * 768;
        const int b = bg * 4 + bi;
        float v;
        if (k < 256) v = context[b * DENC + k];
        else v = (t > 0) ? Hall[(size_t)(t - 1) * BH + b * HH + (k - 256)] : 0.f;
        xs[bi][k] = v;
    }
    __syncthreads();

    const int kq = tid >> 8;             // 0..3, wave-uniform
    const int r = tid & 255;
    const int jl = r & 63, bl = r >> 6;
    const int j = jc * 64 + jl;
    const float* xrow = xs[bl];

    float acc = 0.f;
    if (kq == 0) {
        // k 0..191: context part, Wih rows 512..703
        const float* W1 = Wih + (size_t)512 * G4 + j;
        #pragma unroll 16
        for (int k = 0; k < 192; ++k) acc += xrow[k] * W1[(size_t)k * G4];
    } else if (kq == 1) {
        // k 192..255: context, Wih rows 704..767; k 256..383: Whh rows 0..127
        const float* W1 = Wih + (size_t)704 * G4 + j;
        #pragma unroll 16
        for (int k = 0; k < 64; ++k) acc += xrow[192 + k] * W1[(size_t)k * G4];
        const float* W2 = Whh + j;
        #pragma unroll 16
        for (int k = 0; k < 128; ++k) acc += xrow[256 + k] * W2[(size_t)k * G4];
    } else if (kq == 2) {
        // Whh rows 128..319
        const float* W2 = Whh + (size_t)128 * G4 + j;
        #pragma unroll 16
        for (int k = 0; k < 192; ++k) acc += xrow[384 + k] * W2[(size_t)k * G4];
    } else {
        // Whh rows 320..511
        const float* W2 = Whh + (size_t)320 * G4 + j;
        #pragma unroll 16
        for (int k = 0; k < 192; ++k) acc += xrow[576 + k] * W2[(size_t)k * G4];
    }
    part[kq][r] = acc;
    __syncthreads();

    if (tid < 256) {
        const int b = bg * 4 + bl;
        gates[(size_t)b * G4 + j] = part[0][tid] + part[1][tid] + part[2][tid] + part[3][tid]
                                  + Epre[(size_t)(t * BB + b) * G4 + j];
    }
}

// ---------------------------------------------------------------------------
// LSTM pointwise update for the final step (t = T-1) -> Hall[T-1]
// ---------------------------------------------------------------------------
__global__ void final_update_kernel(const float* __restrict__ gates,
                                    const float* __restrict__ cbuf,
                                    float* __restrict__ Hall) {
    const int idx = blockIdx.x * 256 + threadIdx.x;   // < 16384
    const int b = idx >> 9, hi = idx & 511;
    const float* g = gates + b * G4;
    const float gi = g[hi];
    const float gf = g[HH + hi];
    const float gg = g[2 * HH + hi];
    const float go = g[3 * HH + hi];
    const float cp = cbuf[idx];
    const float cn = fast_sigmoid(gf) * cp + fast_sigmoid(gi) * fast_tanh(gg);
    const float hn = fast_sigmoid(go) * fast_tanh(cn);
    Hall[(size_t)(TT - 1) * BH + idx] = hn;
}

// ---------------------------------------------------------------------------
// One-time split kernels (pre-split path): fp32 -> hi/lo bf16 tables.
// ---------------------------------------------------------------------------
__global__ void split_hall_kernel(const float* __restrict__ Hall,
                                  unsigned short* __restrict__ Ah,
                                  unsigned short* __restrict__ Al) {
    const int idx = blockIdx.x * 256 + threadIdx.x;   // < 640*512
    unsigned short h, l;
    split_bf16(Hall[idx], h, l);
    Ah[idx] = h; Al[idx] = l;
}

// Transpose + split Wfc[k][v] -> Wt_h/Wt_l[v][k], v padded to VPAD (zero-fill).
// Block: 256 threads handle a 64k x 64v tile.
__global__ void split_wfc_kernel(const float* __restrict__ Wfc,
                                 unsigned short* __restrict__ Wt_h,
                                 unsigned short* __restrict__ Wt_l) {
    __shared__ unsigned short th[64][66];
    __shared__ unsigned short tl[64][66];
    const int tid = threadIdx.x;
    const int k0 = blockIdx.x * 64;     // 8 k-tiles
    const int v0 = blockIdx.y * 64;     // 470 v-tiles (covers VPAD)

    // load: 64 c-lanes x 4 r-rows per pass, 16 passes
    const int c = tid & 63, r0 = tid >> 6;
    #pragma unroll
    for (int i = 0; i < 16; ++i) {
        const int r = r0 + i * 4;
        const int v = v0 + c;
        const float x = (v < VV) ? Wfc[(size_t)(k0 + r) * VV + v] : 0.f;
        unsigned short h, l;
        split_bf16(x, h, l);
        th[r][c] = h; tl[r][c] = l;
    }
    __syncthreads();

    // store transposed: thread -> v = tid>>2, k-quarter = tid&3 (16 k's, 32B)
    const int v = tid >> 2, q = tid & 3;
    short8 oh0, oh1, ol0, ol1;
    #pragma unroll
    for (int i = 0; i < 8; ++i) {
        oh0[i] = (short)th[q * 16 + i][v];
        oh1[i] = (short)th[q * 16 + 8 + i][v];
        ol0[i] = (short)tl[q * 16 + i][v];
        ol1[i] = (short)tl[q * 16 + 8 + i][v];
    }
    unsigned short* dh = Wt_h + (size_t)(v0 + v) * HH + k0 + q * 16;
    unsigned short* dl = Wt_l + (size_t)(v0 + v) * HH + k0 + q * 16;
    *(short8*)(dh) = oh0; *(short8*)(dh + 8) = oh1;
    *(short8*)(dl) = ol0; *(short8*)(dl + 8) = ol1;
}

// ---------------------------------------------------------------------------
// Output projection, pre-split path: pure-copy staging, bf16x3 MFMA.
// 128x128 tile, BK=32, 256 threads (4 waves, each 64x64 of 16x16x32 frags).
// ---------------------------------------------------------------------------
#define LDK 40   // padded LDS row length in bf16 units

__global__ __launch_bounds__(256) void gemm_out_mfma_pre(
        const unsigned short* __restrict__ Ah,
        const unsigned short* __restrict__ Al,
        const unsigned short* __restrict__ Wt_h,
        const unsigned short* __restrict__ Wt_l,
        const float* __restrict__ bfc,
        float* __restrict__ out) {
    __shared__ unsigned short As_h[128 * LDK];
    __shared__ unsigned short As_l[128 * LDK];
    __shared__ unsigned short Bs_h[128 * LDK];
    __shared__ unsigned short Bs_l[128 * LDK];

    const int tid = threadIdx.x;
    const int m0 = blockIdx.x * 128;     // 5 m-tiles (M=640)
    const int v0 = blockIdx.y * 128;     // 235 v-tiles

    const int wave = tid >> 6, lane = tid & 63;
    const int wm = wave & 1, wn = wave >> 1;
    const int row16 = lane & 15, quad = lane >> 4;

    const int sn = tid & 127;            // staging row (m for A, v for B)
    const int skq = tid >> 7;            // staging k-half (16 k's)

    f32x4 acc[4][4] = {};

    #pragma unroll 1
    for (int k0 = 0; k0 < HH; k0 += 32) {
        // ---- stage A (pure copy)
        {
            const size_t src = (size_t)(m0 + sn) * HH + k0 + skq * 16;
            const short8 h0 = *(const short8*)(Ah + src);
            const short8 h1 = *(const short8*)(Ah + src + 8);
            const short8 l0 = *(const short8*)(Al + src);
            const short8 l1 = *(const short8*)(Al + src + 8);
            unsigned short* dh = &As_h[sn * LDK + skq * 16];
            unsigned short* dl = &As_l[sn * LDK + skq * 16];
            *(short8*)(dh) = h0; *(short8*)(dh + 8) = h1;
            *(short8*)(dl) = l0; *(short8*)(dl + 8) = l1;
        }
        // ---- stage B (pure copy, already transposed + zero-padded)
        {
            const size_t src = (size_t)(v0 + sn) * HH + k0 + skq * 16;
            const short8 h0 = *(const short8*)(Wt_h + src);
            const short8 h1 = *(const short8*)(Wt_h + src + 8);
            const short8 l0 = *(const short8*)(Wt_l + src);
            const short8 l1 = *(const short8*)(Wt_l + src + 8);
            unsigned short* dh = &Bs_h[sn * LDK + skq * 16];
            unsigned short* dl = &Bs_l[sn * LDK + skq * 16];
            *(short8*)(dh) = h0; *(short8*)(dh + 8) = h1;
            *(short8*)(dl) = l0; *(short8*)(dl + 8) = l1;
        }
        __syncthreads();

        short8 ah[4], al[4], bh[4], bl[4];
        #pragma unroll
        for (int mi = 0; mi < 4; ++mi) {
            const int off = (wm * 64 + mi * 16 + row16) * LDK + quad * 8;
            ah[mi] = *(const short8*)&As_h[off];
            al[mi] = *(const short8*)&As_l[off];
        }
        #pragma unroll
        for (int ni = 0; ni < 4; ++ni) {
            const int off = (wn * 64 + ni * 16 + row16) * LDK + quad * 8;
            bh[ni] = *(const short8*)&Bs_h[off];
            bl[ni] = *(const short8*)&Bs_l[off];
        }
        #pragma unroll
        for (int mi = 0; mi < 4; ++mi) {
            #pragma unroll
            for (int ni = 0; ni < 4; ++ni) {
                acc[mi][ni] = __builtin_amdgcn_mfma_f32_16x16x32_bf16(
                    ah[mi], bh[ni], acc[mi][ni], 0, 0, 0);
                acc[mi][ni] = __builtin_amdgcn_mfma_f32_16x16x32_bf16(
                    ah[mi], bl[ni], acc[mi][ni], 0, 0, 0);
                acc[mi][ni] = __builtin_amdgcn_mfma_f32_16x16x32_bf16(
                    al[mi], bh[ni], acc[mi][ni], 0, 0, 0);
            }
        }
        __syncthreads();
    }

    // epilogue: C/D layout col=lane&15 (v), row=quad*4+reg (m)
    #pragma unroll
    for (int ni = 0; ni < 4; ++ni) {
        const int v = v0 + wn * 64 + ni * 16 + row16;
        if (v >= VV) continue;
        const float bias = bfc[v];
        #pragma unroll
        for (int mi = 0; mi < 4; ++mi) {
            const int mbase = m0 + wm * 64 + mi * 16 + quad * 4;
            #pragma unroll
            for (int r = 0; r < 4; ++r) {
                const int m = mbase + r;
                const int t_idx = m >> 5;
                const int b_idx = m & 31;
                out[((size_t)b_idx * TT + t_idx) * VV + v] = acc[mi][ni][r] + bias;
            }
        }
    }
}

// ---------------------------------------------------------------------------
// Fallback gemm (in-kernel split) — used when ws is too small for tables.
// ---------------------------------------------------------------------------
__global__ __launch_bounds__(256) void gemm_out_mfma_fb(
        const float* __restrict__ Hall,
        const float* __restrict__ Wfc,
        const float* __restrict__ bfc,
        float* __restrict__ out) {
    __shared__ unsigned short As_h[128 * LDK];
    __shared__ unsigned short As_l[128 * LDK];
    __shared__ unsigned short Bs_h[128 * LDK];
    __shared__ unsigned short Bs_l[128 * LDK];

    const int tid = threadIdx.x;
    const int m0 = blockIdx.x * 128;
    const int v0 = blockIdx.y * 128;

    const int wave = tid >> 6, lane = tid & 63;
    const int wm = wave & 1, wn = wave >> 1;
    const int row16 = lane & 15, quad = lane >> 4;

    const int sn = tid & 127;
    const int skq = tid >> 7;

    f32x4 acc[4][4] = {};

    #pragma unroll 1
    for (int k0 = 0; k0 < HH; k0 += 32) {
        {
            const float* asrc = Hall + (size_t)(m0 + sn) * HH + k0 + skq * 16;
            short8 h0, h1, l0, l1;
            #pragma unroll
            for (int i = 0; i < 16; i += 4) {
                const float4 v = *reinterpret_cast<const float4*>(asrc + i);
                const float vv[4] = {v.x, v.y, v.z, v.w};
                #pragma unroll
                for (int jj = 0; jj < 4; ++jj) {
                    unsigned short hb, lb;
                    split_bf16(vv[jj], hb, lb);
                    const int e = i + jj;
                    if (e < 8) { h0[e] = (short)hb; l0[e] = (short)lb; }
                    else       { h1[e - 8] = (short)hb; l1[e - 8] = (short)lb; }
                }
            }
            unsigned short* dh = &As_h[sn * LDK + skq * 16];
            unsigned short* dl = &As_l[sn * LDK + skq * 16];
            *(short8*)(dh) = h0; *(short8*)(dh + 8) = h1;
            *(short8*)(dl) = l0; *(short8*)(dl + 8) = l1;
        }
        {
            const int vcol = v0 + sn;
            const bool ok = vcol < VV;
            const float* bsrc = Wfc + (size_t)(k0 + skq * 16) * VV + vcol;
            short8 h0, h1, l0, l1;
            #pragma unroll
            for (int i = 0; i < 16; ++i) {
                const float x = ok ? bsrc[(size_t)i * VV] : 0.f;
                unsigned short hb, lb;
                split_bf16(x, hb, lb);
                if (i < 8) { h0[i] = (short)hb; l0[i] = (short)lb; }
                else       { h1[i - 8] = (short)hb; l1[i - 8] = (short)lb; }
            }
            unsigned short* dh = &Bs_h[sn * LDK + skq * 16];
            unsigned short* dl = &Bs_l[sn * LDK + skq * 16];
            *(short8*)(dh) = h0; *(short8*)(dh + 8) = h1;
            *(short8*)(dl) = l0; *(short8*)(dl + 8) = l1;
        }
        __syncthreads();

        short8 ah[4], al[4], bh[4], bl[4];
        #pragma unroll
        for (int mi = 0; mi < 4; ++mi) {
            const int off = (wm * 64 + mi * 16 + row16) * LDK + quad * 8;
            ah[mi] = *(const short8*)&As_h[off];
            al[mi] = *(const short8*)&As_l[off];
        }
        #pragma unroll
        for (int ni = 0; ni < 4; ++ni) {
            const int off = (wn * 64 + ni * 16 + row16) * LDK + quad * 8;
            bh[ni] = *(const short8*)&Bs_h[off];
            bl[ni] = *(const short8*)&Bs_l[off];
        }
        #pragma unroll
        for (int mi = 0; mi < 4; ++mi) {
            #pragma unroll
            for (int ni = 0; ni < 4; ++ni) {
                acc[mi][ni] = __builtin_amdgcn_mfma_f32_16x16x32_bf16(
                    ah[mi], bh[ni], acc[mi][ni], 0, 0, 0);
                acc[mi][ni] = __builtin_amdgcn_mfma_f32_16x16x32_bf16(
                    ah[mi], bl[ni], acc[mi][ni], 0, 0, 0);
                acc[mi][ni] = __builtin_amdgcn_mfma_f32_16x16x32_bf16(
                    al[mi], bh[ni], acc[mi][ni], 0, 0, 0);
            }
        }
        __syncthreads();
    }

    #pragma unroll
    for (int ni = 0; ni < 4; ++ni) {
        const int v = v0 + wn * 64 + ni * 16 + row16;
        if (v >= VV) continue;
        const float bias = bfc[v];
        #pragma unroll
        for (int mi = 0; mi < 4; ++mi) {
            const int mbase = m0 + wm * 64 + mi * 16 + quad * 4;
            #pragma unroll
            for (int r = 0; r < 4; ++r) {
                const int m = mbase + r;
                const int t_idx = m >> 5;
                const int b_idx = m & 31;
                out[((size_t)b_idx * TT + t_idx) * VV + v] = acc[mi][ni][r] + bias;
            }
        }
    }
}

// ---------------------------------------------------------------------------
extern "C" void kernel_launch(void* const* d_in, const int* in_sizes, int n_in,
                              void* d_out, int out_size, void* d_ws, size_t ws_size,
                              hipStream_t stream) {
    const float* enc      = (const float*)d_in[0];
    const int*   captions = (const int*)  d_in[1];
    const float* Wea      = (const float*)d_in[2];
    const float* bea      = (const float*)d_in[3];
    const float* Wda      = (const float*)d_in[4];
    const float* bda      = (const float*)d_in[5];
    const float* Wfull    = (const float*)d_in[6];
    const float* bfull    = (const float*)d_in[7];
    const float* emb      = (const float*)d_in[8];
    const float* Wih      = (const float*)d_in[9];
    const float* bih      = (const float*)d_in[10];
    const float* Whh      = (const float*)d_in[11];
    const float* bhh      = (const float*)d_in[12];
    const float* Wfc      = (const float*)d_in[13];
    const float* bfc      = (const float*)d_in[14];
    float* out = (float*)d_out;

    float* ws      = (float*)d_ws;
    float* att1    = ws;                        // 1,605,632 f
    float* Hall    = att1 + 1605632;            //   327,680 f
    float* cbuf    = Hall + 327680;             //    16,384 f
    float* context = cbuf + 16384;              //     8,192 f
    float* gates   = context + 8192;            //    65,536 f
    float* Epre    = gates + 65536;             // 1,310,720 f
    float* tail    = Epre + 1310720;            // tables start here
    // bf16 tables (as ushort), sizes in floats (2 shorts per float):
    unsigned short* Ah   = (unsigned short*)tail;              // 640*512
    unsigned short* Al   = Ah + 640 * 512;
    unsigned short* Wt_h = Al + 640 * 512;                     // VPAD*512
    unsigned short* Wt_l = Wt_h + (size_t)VPAD * HH;
    const size_t need_bytes =
        (size_t)(3334144) * 4 +                       // fp32 scratch
        (size_t)(2 * 640 * 512) * 2 +                 // Ah/Al
        (size_t)(2 * (size_t)VPAD * HH) * 2;          // Wt_h/Wt_l
    const bool pre = ws_size >= need_bytes;

    att1_kernel<<<dim3(784), dim3(256), 0, stream>>>(enc, Wea, bea, att1);
    epre_kernel<<<dim3(8, 80), dim3(256), 0, stream>>>(captions, emb, Wih, bih, bhh, Epre);
    if (pre) {
        split_wfc_kernel<<<dim3(8, VPAD / 64), dim3(256), 0, stream>>>(Wfc, Wt_h, Wt_l);
    }

    for (int t = 0; t < TT; ++t) {
        attn_step_kernel<<<dim3(BB), dim3(1024), 0, stream>>>(
            t, att1, enc, Hall, cbuf, gates, context, Wda, bda, Wfull, bfull);
        gates_kernel<<<dim3(32, 8), dim3(1024), 0, stream>>>(
            t, context, Hall, Epre, Wih, Whh, gates);
    }
    final_update_kernel<<<dim3(64), dim3(256), 0, stream>>>(gates, cbuf, Hall);

    if (pre) {
        split_hall_kernel<<<dim3(1280), dim3(256), 0, stream>>>(Hall, Ah, Al);
        gemm_out_mfma_pre<<<dim3(5, 235), dim3(256), 0, stream>>>(
            Ah, Al, Wt_h, Wt_l, bfc, out);
    } else {
        gemm_out_mfma_fb<<<dim3(5, 235), dim3(256), 0, stream>>>(Hall, Wfc, bfc, out);
    }
}